// Round 1
// baseline (346.383 us; speedup 1.0000x reference)
//
#include <hip/hip_runtime.h>
#include <hip/hip_bf16.h>

#define BB 2
#define SS 2048
#define DD 1024
#define HH 16
#define DK 64
#define MM (BB*SS)   // 4096

typedef __attribute__((ext_vector_type(8))) short bf16x8;
typedef __attribute__((ext_vector_type(4))) float f32x4;

__device__ inline ushort f2bf(float f) {
  __hip_bfloat16 h = __float2bfloat16(f);
  return *reinterpret_cast<ushort*>(&h);
}

// ---------------- fp32 -> bf16 convert (float4 vectorized) ----------------
__global__ void cvt_f32_bf16(const float* __restrict__ src, ushort* __restrict__ dst, int n4) {
  int i = blockIdx.x * blockDim.x + threadIdx.x;
  int stride = gridDim.x * blockDim.x;
  for (int idx = i; idx < n4; idx += stride) {
    float4 v = reinterpret_cast<const float4*>(src)[idx];
    ushort4 o;
    o.x = f2bf(v.x); o.y = f2bf(v.y); o.z = f2bf(v.z); o.w = f2bf(v.w);
    reinterpret_cast<ushort4*>(dst)[idx] = o;
  }
}

// ---------------- GEMM NT: C[m,e] = sum_k A[m,k] * W[e,k]  (+bias)*scale ----
// LAYOUT 0: bf16 out, [B,H,S,DK] (for Q,K)
// LAYOUT 1: bf16 out, [B,H,DK,S] (for V, transposed)
// LAYOUT 2: fp32 out, [M,N] flat (final projection)
template<int LAYOUT>
__global__ __launch_bounds__(256) void gemm_nt(const ushort* __restrict__ A,
                                               const ushort* __restrict__ W,
                                               const float* __restrict__ bias,
                                               void* __restrict__ out,
                                               float scale) {
  constexpr int K = 1024;
  __shared__ __align__(16) ushort lds_a[128 * 72];
  __shared__ __align__(16) ushort lds_b[128 * 72];
  const int t = threadIdx.x;
  const int m0 = blockIdx.y * 128;
  const int n0 = blockIdx.x * 128;
  const int lane = t & 63;
  const int w = t >> 6;
  const int wm = (w >> 1) * 64, wn = (w & 1) * 64;
  const int c = lane & 15, g = lane >> 4;

  f32x4 acc[4][4];
  #pragma unroll
  for (int i = 0; i < 4; i++)
    #pragma unroll
    for (int j = 0; j < 4; j++) acc[i][j] = f32x4{0.f, 0.f, 0.f, 0.f};

  const int srow = t >> 3;          // 0..31
  const int schunk = (t & 7) * 8;   // element offset within 64-wide K slab

  for (int k0 = 0; k0 < K; k0 += 64) {
    #pragma unroll
    for (int i = 0; i < 4; i++) {
      int r = srow + i * 32;
      *reinterpret_cast<bf16x8*>(&lds_a[r * 72 + schunk]) =
          *reinterpret_cast<const bf16x8*>(&A[(m0 + r) * K + k0 + schunk]);
      *reinterpret_cast<bf16x8*>(&lds_b[r * 72 + schunk]) =
          *reinterpret_cast<const bf16x8*>(&W[(n0 + r) * K + k0 + schunk]);
    }
    __syncthreads();
    #pragma unroll
    for (int kk = 0; kk < 64; kk += 32) {
      bf16x8 af[4], bfr[4];
      #pragma unroll
      for (int mi = 0; mi < 4; mi++)
        af[mi] = *reinterpret_cast<const bf16x8*>(&lds_a[(wm + mi * 16 + c) * 72 + kk + g * 8]);
      #pragma unroll
      for (int ni = 0; ni < 4; ni++)
        bfr[ni] = *reinterpret_cast<const bf16x8*>(&lds_b[(wn + ni * 16 + c) * 72 + kk + g * 8]);
      #pragma unroll
      for (int mi = 0; mi < 4; mi++)
        #pragma unroll
        for (int ni = 0; ni < 4; ni++)
          acc[mi][ni] = __builtin_amdgcn_mfma_f32_16x16x32_bf16(af[mi], bfr[ni], acc[mi][ni], 0, 0, 0);
    }
    __syncthreads();
  }

  #pragma unroll
  for (int mi = 0; mi < 4; mi++) {
    #pragma unroll
    for (int ni = 0; ni < 4; ni++) {
      int colb = n0 + wn + ni * 16 + c;
      float bv = bias[colb];
      #pragma unroll
      for (int j = 0; j < 4; j++) {
        int row = m0 + wm + mi * 16 + g * 4 + j;
        float val = (acc[mi][ni][j] + bv) * scale;
        if (LAYOUT == 0) {        // bf16 [B,H,S,DK]
          int b = row >> 11, s = row & 2047, h = colb >> 6, dk = colb & 63;
          reinterpret_cast<ushort*>(out)[(((b * HH + h) * SS + s) << 6) + dk] = f2bf(val);
        } else if (LAYOUT == 1) { // bf16 [B,H,DK,S]
          int b = row >> 11, s = row & 2047, h = colb >> 6, dk = colb & 63;
          reinterpret_cast<ushort*>(out)[(((b * HH + h) * DK + dk) << 11) + s] = f2bf(val);
        } else {                  // fp32 [M,N]
          reinterpret_cast<float*>(out)[(row << 10) + colb] = val;
        }
      }
    }
  }
}

// ---------------- causal flash attention ----------------
// Q,K: [B,H,S,DK] bf16 (Q pre-scaled by 1/sqrt(DK)); V: [B,H,DK,S] bf16
// O: [B,S,D] bf16
__global__ __launch_bounds__(256) void attn_fwd(const ushort* __restrict__ Q,
                                                const ushort* __restrict__ Kk,
                                                const ushort* __restrict__ Vt,
                                                ushort* __restrict__ O) {
  __shared__ __align__(16) ushort lds_p[4][16 * 72];
  const int t = threadIdx.x;
  const int w = t >> 6;
  const int lane = t & 63;
  const int c = lane & 15, g = lane >> 4;
  const int bh = blockIdx.y;            // 0..B*H-1
  const int q0 = blockIdx.x * 64;
  const int qw0 = q0 + w * 16;
  const ushort* qbase = Q + (size_t)bh * SS * DK;
  const ushort* kbase = Kk + (size_t)bh * SS * DK;
  const ushort* vbase = Vt + (size_t)bh * DK * SS;

  bf16x8 qf0 = *reinterpret_cast<const bf16x8*>(&qbase[(qw0 + c) * DK + g * 8]);
  bf16x8 qf1 = *reinterpret_cast<const bf16x8*>(&qbase[(qw0 + c) * DK + 32 + g * 8]);

  f32x4 o_acc[4];
  #pragma unroll
  for (int i = 0; i < 4; i++) o_acc[i] = f32x4{0.f, 0.f, 0.f, 0.f};
  float m_run[4], l_run[4];
  #pragma unroll
  for (int j = 0; j < 4; j++) { m_run[j] = -1e30f; l_run[j] = 0.f; }

  ushort* pb = lds_p[w];

  for (int kv = 0; kv < qw0 + 16; kv += 64) {
    // ---- S = Q K^T (scaled already) ----
    f32x4 s[4];
    #pragma unroll
    for (int tt = 0; tt < 4; tt++) {
      const ushort* kr = &kbase[(kv + tt * 16 + c) * DK + g * 8];
      bf16x8 kf0 = *reinterpret_cast<const bf16x8*>(kr);
      bf16x8 kf1 = *reinterpret_cast<const bf16x8*>(kr + 32);
      f32x4 z = {0.f, 0.f, 0.f, 0.f};
      z = __builtin_amdgcn_mfma_f32_16x16x32_bf16(qf0, kf0, z, 0, 0, 0);
      s[tt] = __builtin_amdgcn_mfma_f32_16x16x32_bf16(qf1, kf1, z, 0, 0, 0);
    }
    // ---- causal mask (only near/above diagonal) ----
    if (kv + 63 > qw0) {
      #pragma unroll
      for (int tt = 0; tt < 4; tt++) {
        int kj = kv + tt * 16 + c;
        #pragma unroll
        for (int j = 0; j < 4; j++) {
          int r = qw0 + g * 4 + j;
          if (kj > r) s[tt][j] = -1e30f;
        }
      }
    }
    // ---- online softmax ----
    float mn[4], alpha[4];
    #pragma unroll
    for (int j = 0; j < 4; j++) {
      float m1 = fmaxf(fmaxf(s[0][j], s[1][j]), fmaxf(s[2][j], s[3][j]));
      #pragma unroll
      for (int off = 1; off < 16; off <<= 1)
        m1 = fmaxf(m1, __shfl_xor(m1, off, 16));
      mn[j] = fmaxf(m_run[j], m1);
      alpha[j] = __expf(m_run[j] - mn[j]);
      m_run[j] = mn[j];
    }
    float psum[4] = {0.f, 0.f, 0.f, 0.f};
    #pragma unroll
    for (int tt = 0; tt < 4; tt++) {
      #pragma unroll
      for (int j = 0; j < 4; j++) {
        float p = __expf(s[tt][j] - mn[j]);
        psum[j] += p;
        pb[(g * 4 + j) * 72 + tt * 16 + c] = f2bf(p);
      }
    }
    #pragma unroll
    for (int j = 0; j < 4; j++) {
      float ps = psum[j];
      #pragma unroll
      for (int off = 1; off < 16; off <<= 1)
        ps += __shfl_xor(ps, off, 16);
      l_run[j] = l_run[j] * alpha[j] + ps;
      #pragma unroll
      for (int dt = 0; dt < 4; dt++) o_acc[dt][j] *= alpha[j];
    }
    // ---- O += P V ----
    #pragma unroll
    for (int kk2 = 0; kk2 < 2; kk2++) {
      bf16x8 pa = *reinterpret_cast<const bf16x8*>(&pb[c * 72 + kk2 * 32 + g * 8]);
      #pragma unroll
      for (int dt = 0; dt < 4; dt++) {
        bf16x8 vf = *reinterpret_cast<const bf16x8*>(&vbase[(dt * 16 + c) * SS + kv + kk2 * 32 + g * 8]);
        o_acc[dt] = __builtin_amdgcn_mfma_f32_16x16x32_bf16(pa, vf, o_acc[dt], 0, 0, 0);
      }
    }
  }

  const int b = bh >> 4, h = bh & 15;
  #pragma unroll
  for (int dt = 0; dt < 4; dt++) {
    #pragma unroll
    for (int j = 0; j < 4; j++) {
      int row = qw0 + g * 4 + j;
      float val = o_acc[dt][j] / l_run[j];
      O[((size_t)(b * SS + row) << 10) + h * DK + dt * 16 + c] = f2bf(val);
    }
  }
}

// ---------------- launch ----------------
extern "C" void kernel_launch(void* const* d_in, const int* in_sizes, int n_in,
                              void* d_out, int out_size, void* d_ws, size_t ws_size,
                              hipStream_t stream) {
  const float* x  = (const float*)d_in[0];
  const float* wq = (const float*)d_in[2];
  const float* bq = (const float*)d_in[3];
  const float* wk = (const float*)d_in[4];
  const float* bk = (const float*)d_in[5];
  const float* wv = (const float*)d_in[6];
  const float* bv = (const float*)d_in[7];
  const float* wo = (const float*)d_in[8];
  const float* bo = (const float*)d_in[9];

  ushort* ws = (ushort*)d_ws;
  ushort* xb = ws;                        // 4096*1024 bf16 (x) ; later reused as attn out
  ushort* wb = xb + (size_t)MM * DD;      // 1024*1024 bf16 (current weight)
  ushort* qw = wb + (size_t)DD * DD;      // 4096*1024 bf16 [B,H,S,DK]
  ushort* kw = qw + (size_t)MM * DD;      // 4096*1024 bf16 [B,H,S,DK]
  ushort* vw = kw + (size_t)MM * DD;      // 4096*1024 bf16 [B,H,DK,S]
  ushort* aw = xb;                        // attn output aliases xb (xb dead after V gemm)

  dim3 gg(DD / 128, MM / 128);

  cvt_f32_bf16<<<2048, 256, 0, stream>>>(x, xb, MM * DD / 4);

  cvt_f32_bf16<<<512, 256, 0, stream>>>(wq, wb, DD * DD / 4);
  gemm_nt<0><<<gg, 256, 0, stream>>>(xb, wb, bq, qw, 0.125f);   // Q, pre-scaled 1/sqrt(64)

  cvt_f32_bf16<<<512, 256, 0, stream>>>(wk, wb, DD * DD / 4);
  gemm_nt<0><<<gg, 256, 0, stream>>>(xb, wb, bk, kw, 1.0f);     // K

  cvt_f32_bf16<<<512, 256, 0, stream>>>(wv, wb, DD * DD / 4);
  gemm_nt<1><<<gg, 256, 0, stream>>>(xb, wb, bv, vw, 1.0f);     // V (transposed [B,H,DK,S])

  attn_fwd<<<dim3(SS / 64, BB * HH), 256, 0, stream>>>(qw, kw, vw, aw);

  cvt_f32_bf16<<<512, 256, 0, stream>>>(wo, wb, DD * DD / 4);
  gemm_nt<2><<<gg, 256, 0, stream>>>(aw, wb, bo, d_out, 1.0f);  // final, fp32 out
}

// Round 2
// 231.986 us; speedup vs baseline: 1.4931x; 1.4931x over previous
//
#include <hip/hip_runtime.h>
#include <hip/hip_bf16.h>

#define BB 2
#define SS 2048
#define DD 1024
#define HH 16
#define DK 64
#define MM (BB*SS)   // 4096

typedef __attribute__((ext_vector_type(8))) short bf16x8;
typedef __attribute__((ext_vector_type(4))) float f32x4;

__device__ inline ushort f2bf(float f) {
  __hip_bfloat16 h = __float2bfloat16(f);
  return *reinterpret_cast<ushort*>(&h);
}

// ---------------- fp32 -> bf16 convert (float4 vectorized) ----------------
__global__ void cvt_f32_bf16(const float* __restrict__ src, ushort* __restrict__ dst, int n4) {
  int i = blockIdx.x * blockDim.x + threadIdx.x;
  int stride = gridDim.x * blockDim.x;
  for (int idx = i; idx < n4; idx += stride) {
    float4 v = reinterpret_cast<const float4*>(src)[idx];
    ushort4 o;
    o.x = f2bf(v.x); o.y = f2bf(v.y); o.z = f2bf(v.z); o.w = f2bf(v.w);
    reinterpret_cast<ushort4*>(dst)[idx] = o;
  }
}

// ---------------- GEMM NT: C[m,e] = sum_k A[m,k] * W[e,k]  (+bias)*scale ----
// LAYOUT 0: bf16 out, [B,H,S,DK] (for Q,K)
// LAYOUT 1: bf16 out, [B,H,DK,S] (for V, transposed)
// LAYOUT 2: fp32 out, [M,N] flat (final projection)
template<int LAYOUT>
__global__ __launch_bounds__(256) void gemm_nt(const ushort* __restrict__ A,
                                               const ushort* __restrict__ W,
                                               const float* __restrict__ bias,
                                               void* __restrict__ out,
                                               float scale) {
  constexpr int K = 1024;
  __shared__ __align__(16) ushort lds_a[128 * 72];
  __shared__ __align__(16) ushort lds_b[128 * 72];
  const int t = threadIdx.x;
  const int m0 = blockIdx.y * 128;
  const int n0 = blockIdx.x * 128;
  const int lane = t & 63;
  const int w = t >> 6;
  const int wm = (w >> 1) * 64, wn = (w & 1) * 64;
  const int c = lane & 15, g = lane >> 4;

  f32x4 acc[4][4];
  #pragma unroll
  for (int i = 0; i < 4; i++)
    #pragma unroll
    for (int j = 0; j < 4; j++) acc[i][j] = f32x4{0.f, 0.f, 0.f, 0.f};

  const int srow = t >> 3;          // 0..31
  const int schunk = (t & 7) * 8;   // element offset within 64-wide K slab

  for (int k0 = 0; k0 < K; k0 += 64) {
    #pragma unroll
    for (int i = 0; i < 4; i++) {
      int r = srow + i * 32;
      *reinterpret_cast<bf16x8*>(&lds_a[r * 72 + schunk]) =
          *reinterpret_cast<const bf16x8*>(&A[(m0 + r) * K + k0 + schunk]);
      *reinterpret_cast<bf16x8*>(&lds_b[r * 72 + schunk]) =
          *reinterpret_cast<const bf16x8*>(&W[(n0 + r) * K + k0 + schunk]);
    }
    __syncthreads();
    #pragma unroll
    for (int kk = 0; kk < 64; kk += 32) {
      bf16x8 af[4], bfr[4];
      #pragma unroll
      for (int mi = 0; mi < 4; mi++)
        af[mi] = *reinterpret_cast<const bf16x8*>(&lds_a[(wm + mi * 16 + c) * 72 + kk + g * 8]);
      #pragma unroll
      for (int ni = 0; ni < 4; ni++)
        bfr[ni] = *reinterpret_cast<const bf16x8*>(&lds_b[(wn + ni * 16 + c) * 72 + kk + g * 8]);
      #pragma unroll
      for (int mi = 0; mi < 4; mi++)
        #pragma unroll
        for (int ni = 0; ni < 4; ni++)
          acc[mi][ni] = __builtin_amdgcn_mfma_f32_16x16x32_bf16(af[mi], bfr[ni], acc[mi][ni], 0, 0, 0);
    }
    __syncthreads();
  }

  #pragma unroll
  for (int mi = 0; mi < 4; mi++) {
    #pragma unroll
    for (int ni = 0; ni < 4; ni++) {
      int colb = n0 + wn + ni * 16 + c;
      float bv = bias[colb];
      #pragma unroll
      for (int j = 0; j < 4; j++) {
        int row = m0 + wm + mi * 16 + g * 4 + j;
        float val = (acc[mi][ni][j] + bv) * scale;
        if (LAYOUT == 0) {        // bf16 [B,H,S,DK]
          int b = row >> 11, s = row & 2047, h = colb >> 6, dk = colb & 63;
          reinterpret_cast<ushort*>(out)[(((b * HH + h) * SS + s) << 6) + dk] = f2bf(val);
        } else if (LAYOUT == 1) { // bf16 [B,H,DK,S]
          int b = row >> 11, s = row & 2047, h = colb >> 6, dk = colb & 63;
          reinterpret_cast<ushort*>(out)[(((b * HH + h) * DK + dk) << 11) + s] = f2bf(val);
        } else {                  // fp32 [M,N]
          reinterpret_cast<float*>(out)[(row << 10) + colb] = val;
        }
      }
    }
  }
}

// ---------------- causal flash attention v2 ----------------
// Q,K: [B,H,S,DK] bf16 (Q pre-scaled by 1/sqrt(DK)); V: [B,H,DK,S] bf16
// O: [B,S,D] bf16
// Each wave owns TWO 16-row strips: a and 127-a (mirror pairing -> uniform work).
// K double-buffered in registers (prefetch next tile); K/V loads shared by both strips.
__global__ __launch_bounds__(256, 2) void attn_fwd(const ushort* __restrict__ Q,
                                                   const ushort* __restrict__ Kk,
                                                   const ushort* __restrict__ Vt,
                                                   ushort* __restrict__ O) {
  __shared__ __align__(16) ushort lds_p[4][2][16 * 72];
  const int t0 = threadIdx.x;
  const int w = t0 >> 6;
  const int lane = t0 & 63;
  const int c = lane & 15, g = lane >> 4;
  const int bh = blockIdx.y;                 // 0..B*H-1
  const int a = blockIdx.x * 4 + w;          // 0..63  (strip A); strip B = 127-a
  const int rb0 = a * 16;                    // rows of strip A
  const int rb1 = 2032 - a * 16;             // rows of strip B (mirror)

  const ushort* qbase = Q + (size_t)bh * SS * DK;
  const ushort* kbase = Kk + (size_t)bh * SS * DK;
  const ushort* vbase = Vt + (size_t)bh * DK * SS;

  bf16x8 qf[2][2];
  qf[0][0] = *reinterpret_cast<const bf16x8*>(&qbase[(rb0 + c) * DK + g * 8]);
  qf[0][1] = *reinterpret_cast<const bf16x8*>(&qbase[(rb0 + c) * DK + 32 + g * 8]);
  qf[1][0] = *reinterpret_cast<const bf16x8*>(&qbase[(rb1 + c) * DK + g * 8]);
  qf[1][1] = *reinterpret_cast<const bf16x8*>(&qbase[(rb1 + c) * DK + 32 + g * 8]);

  f32x4 oacc[2][4];
  float m_run[2][4], l_run[2][4];
  #pragma unroll
  for (int f = 0; f < 2; f++) {
    #pragma unroll
    for (int i = 0; i < 4; i++) oacc[f][i] = f32x4{0.f, 0.f, 0.f, 0.f};
    #pragma unroll
    for (int j = 0; j < 4; j++) { m_run[f][j] = -1e30f; l_run[f][j] = 0.f; }
  }

  const int itB = (rb1 + 79) >> 6;           // number of kv tiles for strip B (superset of A's)

  bf16x8 kbuf[2][8];
  #pragma unroll
  for (int i = 0; i < 8; i++)
    kbuf[0][i] = *reinterpret_cast<const bf16x8*>(
        &kbase[((i >> 1) * 16 + c) * DK + (i & 1) * 32 + g * 8]);

  for (int tp = 0; tp < itB; tp += 2) {
    #pragma unroll
    for (int half = 0; half < 2; half++) {
      const int t = tp + half;
      if (t < itB) {
        const int kv = t * 64;
        const bool actA = kv < rb0 + 16;

        // ---- QK^T for both strips (K tile shared) ----
        f32x4 s[2][4];
        __builtin_amdgcn_s_setprio(1);
        #pragma unroll
        for (int tt = 0; tt < 4; tt++) {
          f32x4 z = {0.f, 0.f, 0.f, 0.f};
          z = __builtin_amdgcn_mfma_f32_16x16x32_bf16(qf[1][0], kbuf[half][tt * 2], z, 0, 0, 0);
          s[1][tt] = __builtin_amdgcn_mfma_f32_16x16x32_bf16(qf[1][1], kbuf[half][tt * 2 + 1], z, 0, 0, 0);
        }
        if (actA) {
          #pragma unroll
          for (int tt = 0; tt < 4; tt++) {
            f32x4 z = {0.f, 0.f, 0.f, 0.f};
            z = __builtin_amdgcn_mfma_f32_16x16x32_bf16(qf[0][0], kbuf[half][tt * 2], z, 0, 0, 0);
            s[0][tt] = __builtin_amdgcn_mfma_f32_16x16x32_bf16(qf[0][1], kbuf[half][tt * 2 + 1], z, 0, 0, 0);
          }
        }
        __builtin_amdgcn_s_setprio(0);

        // ---- issue V(t) loads, then prefetch K(t+1) (both in flight during softmax) ----
        bf16x8 vf[8];
        #pragma unroll
        for (int i = 0; i < 8; i++)
          vf[i] = *reinterpret_cast<const bf16x8*>(
              &vbase[((i >> 1) * 16 + c) * SS + kv + (i & 1) * 32 + g * 8]);
        if (t + 1 < itB) {
          const int kvn = kv + 64;
          #pragma unroll
          for (int i = 0; i < 8; i++)
            kbuf[half ^ 1][i] = *reinterpret_cast<const bf16x8*>(
                &kbase[(kvn + (i >> 1) * 16 + c) * DK + (i & 1) * 32 + g * 8]);
        }

        // ---- mask + online softmax + P->LDS, per strip ----
        #pragma unroll
        for (int f = 0; f < 2; f++) {
          if (f == 1 || actA) {
            const int rbf = (f == 0) ? rb0 : rb1;
            if (kv + 63 > rbf) {
              #pragma unroll
              for (int tt = 0; tt < 4; tt++) {
                int kj = kv + tt * 16 + c;
                #pragma unroll
                for (int j = 0; j < 4; j++) {
                  int r = rbf + g * 4 + j;
                  if (kj > r) s[f][tt][j] = -1e30f;
                }
              }
            }
            float mn[4], alpha[4];
            #pragma unroll
            for (int j = 0; j < 4; j++) {
              float m1 = fmaxf(fmaxf(s[f][0][j], s[f][1][j]), fmaxf(s[f][2][j], s[f][3][j]));
              #pragma unroll
              for (int off = 1; off < 16; off <<= 1)
                m1 = fmaxf(m1, __shfl_xor(m1, off, 16));
              mn[j] = fmaxf(m_run[f][j], m1);
              alpha[j] = __expf(m_run[f][j] - mn[j]);
              m_run[f][j] = mn[j];
            }
            ushort* pb = &lds_p[w][f][0];
            float psum[4] = {0.f, 0.f, 0.f, 0.f};
            #pragma unroll
            for (int tt = 0; tt < 4; tt++) {
              #pragma unroll
              for (int j = 0; j < 4; j++) {
                float p = __expf(s[f][tt][j] - mn[j]);
                psum[j] += p;
                pb[(g * 4 + j) * 72 + tt * 16 + c] = f2bf(p);
              }
            }
            #pragma unroll
            for (int j = 0; j < 4; j++) {
              float ps = psum[j];
              #pragma unroll
              for (int off = 1; off < 16; off <<= 1)
                ps += __shfl_xor(ps, off, 16);
              l_run[f][j] = l_run[f][j] * alpha[j] + ps;
              #pragma unroll
              for (int dt = 0; dt < 4; dt++) oacc[f][dt][j] *= alpha[j];
            }
          }
        }

        // ---- O += P V for both strips (V tile shared) ----
        __builtin_amdgcn_s_setprio(1);
        #pragma unroll
        for (int f = 0; f < 2; f++) {
          if (f == 1 || actA) {
            const ushort* pb = &lds_p[w][f][0];
            #pragma unroll
            for (int kk2 = 0; kk2 < 2; kk2++) {
              bf16x8 pa = *reinterpret_cast<const bf16x8*>(&pb[c * 72 + kk2 * 32 + g * 8]);
              #pragma unroll
              for (int dt = 0; dt < 4; dt++)
                oacc[f][dt] = __builtin_amdgcn_mfma_f32_16x16x32_bf16(pa, vf[dt * 2 + kk2], oacc[f][dt], 0, 0, 0);
            }
          }
        }
        __builtin_amdgcn_s_setprio(0);
      }
    }
  }

  const int b = bh >> 4, h = bh & 15;
  #pragma unroll
  for (int f = 0; f < 2; f++) {
    const int rbf = (f == 0) ? rb0 : rb1;
    #pragma unroll
    for (int dt = 0; dt < 4; dt++) {
      #pragma unroll
      for (int j = 0; j < 4; j++) {
        int row = rbf + g * 4 + j;
        float val = oacc[f][dt][j] / l_run[f][j];
        O[((size_t)(b * SS + row) << 10) + h * DK + dt * 16 + c] = f2bf(val);
      }
    }
  }
}

// ---------------- launch ----------------
extern "C" void kernel_launch(void* const* d_in, const int* in_sizes, int n_in,
                              void* d_out, int out_size, void* d_ws, size_t ws_size,
                              hipStream_t stream) {
  const float* x  = (const float*)d_in[0];
  const float* wq = (const float*)d_in[2];
  const float* bq = (const float*)d_in[3];
  const float* wk = (const float*)d_in[4];
  const float* bk = (const float*)d_in[5];
  const float* wv = (const float*)d_in[6];
  const float* bv = (const float*)d_in[7];
  const float* wo = (const float*)d_in[8];
  const float* bo = (const float*)d_in[9];

  ushort* ws = (ushort*)d_ws;
  ushort* xb = ws;                        // 4096*1024 bf16 (x) ; later reused as attn out
  ushort* wb = xb + (size_t)MM * DD;      // 1024*1024 bf16 (current weight)
  ushort* qw = wb + (size_t)DD * DD;      // 4096*1024 bf16 [B,H,S,DK]
  ushort* kw = qw + (size_t)MM * DD;      // 4096*1024 bf16 [B,H,S,DK]
  ushort* vw = kw + (size_t)MM * DD;      // 4096*1024 bf16 [B,H,DK,S]
  ushort* aw = xb;                        // attn output aliases xb (xb dead after V gemm)

  dim3 gg(DD / 128, MM / 128);

  cvt_f32_bf16<<<2048, 256, 0, stream>>>(x, xb, MM * DD / 4);

  cvt_f32_bf16<<<512, 256, 0, stream>>>(wq, wb, DD * DD / 4);
  gemm_nt<0><<<gg, 256, 0, stream>>>(xb, wb, bq, qw, 0.125f);   // Q, pre-scaled 1/sqrt(64)

  cvt_f32_bf16<<<512, 256, 0, stream>>>(wk, wb, DD * DD / 4);
  gemm_nt<0><<<gg, 256, 0, stream>>>(xb, wb, bk, kw, 1.0f);     // K

  cvt_f32_bf16<<<512, 256, 0, stream>>>(wv, wb, DD * DD / 4);
  gemm_nt<1><<<gg, 256, 0, stream>>>(xb, wb, bv, vw, 1.0f);     // V (transposed [B,H,DK,S])

  attn_fwd<<<dim3(16, BB * HH), 256, 0, stream>>>(qw, kw, vw, aw);

  cvt_f32_bf16<<<512, 256, 0, stream>>>(wo, wb, DD * DD / 4);
  gemm_nt<2><<<gg, 256, 0, stream>>>(aw, wb, bo, d_out, 1.0f);  // final, fp32 out
}

// Round 3
// 173.386 us; speedup vs baseline: 1.9978x; 1.3380x over previous
//
#include <hip/hip_runtime.h>
#include <hip/hip_bf16.h>

#define BB 2
#define SS 2048
#define DD 1024
#define HH 16
#define DK 64
#define MM (BB*SS)   // 4096

typedef __attribute__((ext_vector_type(8))) short bf16x8;
typedef __attribute__((ext_vector_type(4))) float f32x4;

__device__ inline ushort f2bf(float f) {
  __hip_bfloat16 h = __float2bfloat16(f);
  return *reinterpret_cast<ushort*>(&h);
}

// async global->LDS, 16B per lane. ldst must be wave-uniform; HW adds lane*16.
__device__ __forceinline__ void gl_lds16(const ushort* g, ushort* l) {
  __builtin_amdgcn_global_load_lds((const __attribute__((address_space(1))) void*)g,
                                   (__attribute__((address_space(3))) void*)l, 16, 0, 0);
}

// ---------------- fp32 -> bf16 convert (float4 vectorized) ----------------
__global__ void cvt_f32_bf16(const float* __restrict__ src, ushort* __restrict__ dst, int n4) {
  int i = blockIdx.x * blockDim.x + threadIdx.x;
  int stride = gridDim.x * blockDim.x;
  for (int idx = i; idx < n4; idx += stride) {
    float4 v = reinterpret_cast<const float4*>(src)[idx];
    ushort4 o;
    o.x = f2bf(v.x); o.y = f2bf(v.y); o.z = f2bf(v.z); o.w = f2bf(v.w);
    reinterpret_cast<ushort4*>(dst)[idx] = o;
  }
}

// ---------------- GEMM NT: C[m,e] = sum_k A[m,k] * W[e,k]  (+bias)*scale ----
// 128x128 tile, BK=64, double-buffered LDS staged via global_load_lds,
// XOR-swizzled (inverse-swizzle on global source, swizzle on ds_read).
// LAYOUT 0: bf16 out, [B,H,S,DK] (Q,K)   LAYOUT 1: bf16 out, [B,H,DK,S] (V)
// LAYOUT 2: fp32 out, [M,N] flat (final projection)
template<int LAYOUT>
__global__ __launch_bounds__(256, 2) void gemm_nt(const ushort* __restrict__ A,
                                                  const ushort* __restrict__ W,
                                                  const float* __restrict__ bias,
                                                  void* __restrict__ out,
                                                  float scale) {
  constexpr int K = 1024;
  __shared__ __align__(16) ushort lA[2][128 * 64];
  __shared__ __align__(16) ushort lB[2][128 * 64];
  const int t = threadIdx.x;
  const int w = t >> 6, lane = t & 63;
  const int m0 = blockIdx.y * 128, n0 = blockIdx.x * 128;
  const int wm = (w >> 1) * 64, wn = (w & 1) * 64;
  const int c = lane & 15, g = lane >> 4;

  f32x4 acc[4][4];
  #pragma unroll
  for (int i = 0; i < 4; i++)
    #pragma unroll
    for (int j = 0; j < 4; j++) acc[i][j] = f32x4{0.f, 0.f, 0.f, 0.f};

  // tile = 128 rows x 64 k-elems = 128 rows x 8 chunks(16B). chunk (row,col)
  // in LDS holds global chunk (row, col^(row&7)).
  auto stage = [&](int ks, int buf) {
    const int k0 = ks * 64;
    #pragma unroll
    for (int i = 0; i < 4; i++) {
      int ch = w * 256 + i * 64 + lane;
      int row = ch >> 3;
      int cs = (ch & 7) ^ (row & 7);
      gl_lds16(&A[(size_t)(m0 + row) * K + k0 + cs * 8], &lA[buf][(w * 256 + i * 64) * 8]);
      gl_lds16(&W[(size_t)(n0 + row) * K + k0 + cs * 8], &lB[buf][(w * 256 + i * 64) * 8]);
    }
  };

  stage(0, 0);
  __syncthreads();
  int cur = 0;
  for (int ks = 0; ks < 16; ks++) {
    if (ks + 1 < 16) stage(ks + 1, cur ^ 1);
    #pragma unroll
    for (int kk2 = 0; kk2 < 2; kk2++) {
      bf16x8 af[4], bfr[4];
      #pragma unroll
      for (int mi = 0; mi < 4; mi++) {
        int row = wm + mi * 16 + c;
        af[mi] = *reinterpret_cast<const bf16x8*>(&lA[cur][row * 64 + (((kk2 * 4 + g) ^ (c & 7)) * 8)]);
      }
      #pragma unroll
      for (int ni = 0; ni < 4; ni++) {
        int row = wn + ni * 16 + c;
        bfr[ni] = *reinterpret_cast<const bf16x8*>(&lB[cur][row * 64 + (((kk2 * 4 + g) ^ (c & 7)) * 8)]);
      }
      #pragma unroll
      for (int mi = 0; mi < 4; mi++)
        #pragma unroll
        for (int ni = 0; ni < 4; ni++)
          acc[mi][ni] = __builtin_amdgcn_mfma_f32_16x16x32_bf16(af[mi], bfr[ni], acc[mi][ni], 0, 0, 0);
    }
    __syncthreads();
    cur ^= 1;
  }

  #pragma unroll
  for (int mi = 0; mi < 4; mi++) {
    #pragma unroll
    for (int ni = 0; ni < 4; ni++) {
      int colb = n0 + wn + ni * 16 + c;
      float bv = bias[colb];
      #pragma unroll
      for (int j = 0; j < 4; j++) {
        int row = m0 + wm + mi * 16 + g * 4 + j;
        float val = (acc[mi][ni][j] + bv) * scale;
        if (LAYOUT == 0) {        // bf16 [B,H,S,DK]
          int b = row >> 11, s = row & 2047, h = colb >> 6, dk = colb & 63;
          reinterpret_cast<ushort*>(out)[(((b * HH + h) * SS + s) << 6) + dk] = f2bf(val);
        } else if (LAYOUT == 1) { // bf16 [B,H,DK,S]
          int b = row >> 11, s = row & 2047, h = colb >> 6, dk = colb & 63;
          reinterpret_cast<ushort*>(out)[(((b * HH + h) * DK + dk) << 11) + s] = f2bf(val);
        } else {                  // fp32 [M,N]
          reinterpret_cast<float*>(out)[(row << 10) + colb] = val;
        }
      }
    }
  }
}

// ---------------- causal flash attention v3 ----------------
// Q,K: [B,H,S,DK] bf16 (Q pre-scaled by 1/sqrt(DK)); V: [B,H,DK,S] bf16
// O: [B,S,D] bf16
// 4 waves/block share K/V tiles staged in LDS (global_load_lds, dbuf, XOR swizzle).
// Wave w owns strips a = bx*4+w and 127-a (mirror pairing -> uniform tiles).
__global__ __launch_bounds__(256, 2) void attn_fwd(const ushort* __restrict__ Q,
                                                   const ushort* __restrict__ Kk,
                                                   const ushort* __restrict__ Vt,
                                                   ushort* __restrict__ O) {
  __shared__ __align__(16) ushort ldsK[2][64 * 64];
  __shared__ __align__(16) ushort ldsV[2][64 * 64];
  __shared__ __align__(16) ushort lds_p[4][2][16 * 72];
  const int t0 = threadIdx.x;
  const int w = t0 >> 6;
  const int lane = t0 & 63;
  const int c = lane & 15, g = lane >> 4;
  const int bh = blockIdx.y;                 // 0..B*H-1
  const int bx = blockIdx.x;                 // 0..15
  const int a = bx * 4 + w;                  // 0..63
  const int rb0 = a * 16;                    // strip A rows
  const int rb1 = 2032 - a * 16;             // strip B rows (mirror)
  const int itB = (rb1 + 79) >> 6;           // tiles needed by this wave's strip B
  const int itMax = (2111 - 64 * bx) >> 6;   // block-uniform loop count (max over waves)

  const ushort* qbase = Q + (size_t)bh * SS * DK;
  const ushort* kbase = Kk + (size_t)bh * SS * DK;
  const ushort* vbase = Vt + (size_t)bh * DK * SS;

  bf16x8 qf[2][2];
  qf[0][0] = *reinterpret_cast<const bf16x8*>(&qbase[(rb0 + c) * DK + g * 8]);
  qf[0][1] = *reinterpret_cast<const bf16x8*>(&qbase[(rb0 + c) * DK + 32 + g * 8]);
  qf[1][0] = *reinterpret_cast<const bf16x8*>(&qbase[(rb1 + c) * DK + g * 8]);
  qf[1][1] = *reinterpret_cast<const bf16x8*>(&qbase[(rb1 + c) * DK + 32 + g * 8]);

  f32x4 oacc[2][4];
  float m_run[2][4], l_run[2][4];
  #pragma unroll
  for (int f = 0; f < 2; f++) {
    #pragma unroll
    for (int i = 0; i < 4; i++) oacc[f][i] = f32x4{0.f, 0.f, 0.f, 0.f};
    #pragma unroll
    for (int j = 0; j < 4; j++) { m_run[f][j] = -1e30f; l_run[f][j] = 0.f; }
  }

  // K tile: 64 kv-rows x 64 dk  (row-major, 8 chunks of 16B per row)
  // V tile: 64 dk-rows x 64 kv
  auto stage = [&](int tt, int buf) {
    const int kv = tt * 64;
    #pragma unroll
    for (int i = 0; i < 2; i++) {
      int ch = w * 128 + i * 64 + lane;
      int row = ch >> 3;
      int cs = (ch & 7) ^ (row & 7);
      gl_lds16(&kbase[(kv + row) * DK + cs * 8], &ldsK[buf][(w * 128 + i * 64) * 8]);
      gl_lds16(&vbase[row * SS + kv + cs * 8], &ldsV[buf][(w * 128 + i * 64) * 8]);
    }
  };

  stage(0, 0);
  __syncthreads();
  int cur = 0;

  for (int t = 0; t < itMax; ++t) {
    const int kv = t * 64;
    if (t + 1 < itMax) stage(t + 1, cur ^ 1);
    const bool actB = t < itB;
    const bool actA = kv < rb0 + 16;
    if (actA || actB) {
      // ---- K fragments from LDS (shared by both strips) ----
      bf16x8 kf[8];
      #pragma unroll
      for (int i = 0; i < 8; i++) {
        int tt = i >> 1, kk2 = i & 1;
        kf[i] = *reinterpret_cast<const bf16x8*>(
            &ldsK[cur][(tt * 16 + c) * 64 + (((kk2 * 4 + g) ^ (c & 7)) * 8)]);
      }
      // ---- QK^T ----
      f32x4 s[2][4];
      __builtin_amdgcn_s_setprio(1);
      if (actB) {
        #pragma unroll
        for (int tt = 0; tt < 4; tt++) {
          f32x4 z = {0.f, 0.f, 0.f, 0.f};
          z = __builtin_amdgcn_mfma_f32_16x16x32_bf16(qf[1][0], kf[tt * 2], z, 0, 0, 0);
          s[1][tt] = __builtin_amdgcn_mfma_f32_16x16x32_bf16(qf[1][1], kf[tt * 2 + 1], z, 0, 0, 0);
        }
      }
      if (actA) {
        #pragma unroll
        for (int tt = 0; tt < 4; tt++) {
          f32x4 z = {0.f, 0.f, 0.f, 0.f};
          z = __builtin_amdgcn_mfma_f32_16x16x32_bf16(qf[0][0], kf[tt * 2], z, 0, 0, 0);
          s[0][tt] = __builtin_amdgcn_mfma_f32_16x16x32_bf16(qf[0][1], kf[tt * 2 + 1], z, 0, 0, 0);
        }
      }
      __builtin_amdgcn_s_setprio(0);

      // ---- mask + online softmax + P->LDS, per strip ----
      #pragma unroll
      for (int f = 0; f < 2; f++) {
        const bool act = (f == 0) ? actA : actB;
        if (act) {
          const int rbf = (f == 0) ? rb0 : rb1;
          if (kv + 63 > rbf) {
            #pragma unroll
            for (int tt = 0; tt < 4; tt++) {
              int kj = kv + tt * 16 + c;
              #pragma unroll
              for (int j = 0; j < 4; j++) {
                int r = rbf + g * 4 + j;
                if (kj > r) s[f][tt][j] = -1e30f;
              }
            }
          }
          float mn[4], alpha[4];
          #pragma unroll
          for (int j = 0; j < 4; j++) {
            float m1 = fmaxf(fmaxf(s[f][0][j], s[f][1][j]), fmaxf(s[f][2][j], s[f][3][j]));
            #pragma unroll
            for (int off = 1; off < 16; off <<= 1)
              m1 = fmaxf(m1, __shfl_xor(m1, off, 16));
            mn[j] = fmaxf(m_run[f][j], m1);
            alpha[j] = __expf(m_run[f][j] - mn[j]);
            m_run[f][j] = mn[j];
          }
          ushort* pb = &lds_p[w][f][0];
          float psum[4] = {0.f, 0.f, 0.f, 0.f};
          #pragma unroll
          for (int tt = 0; tt < 4; tt++) {
            #pragma unroll
            for (int j = 0; j < 4; j++) {
              float p = __expf(s[f][tt][j] - mn[j]);
              psum[j] += p;
              pb[(g * 4 + j) * 72 + tt * 16 + c] = f2bf(p);
            }
          }
          #pragma unroll
          for (int j = 0; j < 4; j++) {
            float ps = psum[j];
            #pragma unroll
            for (int off = 1; off < 16; off <<= 1)
              ps += __shfl_xor(ps, off, 16);
            l_run[f][j] = l_run[f][j] * alpha[j] + ps;
            #pragma unroll
            for (int dt = 0; dt < 4; dt++) oacc[f][dt][j] *= alpha[j];
          }
        }
      }

      // ---- V fragments from LDS, then O += P V ----
      bf16x8 vf[8];
      #pragma unroll
      for (int i = 0; i < 8; i++) {
        int dt = i >> 1, kk2 = i & 1;
        vf[i] = *reinterpret_cast<const bf16x8*>(
            &ldsV[cur][(dt * 16 + c) * 64 + (((kk2 * 4 + g) ^ (c & 7)) * 8)]);
      }
      __builtin_amdgcn_s_setprio(1);
      #pragma unroll
      for (int f = 0; f < 2; f++) {
        const bool act = (f == 0) ? actA : actB;
        if (act) {
          const ushort* pb = &lds_p[w][f][0];
          #pragma unroll
          for (int kk2 = 0; kk2 < 2; kk2++) {
            bf16x8 pa = *reinterpret_cast<const bf16x8*>(&pb[c * 72 + kk2 * 32 + g * 8]);
            #pragma unroll
            for (int dt = 0; dt < 4; dt++)
              oacc[f][dt] = __builtin_amdgcn_mfma_f32_16x16x32_bf16(pa, vf[dt * 2 + kk2], oacc[f][dt], 0, 0, 0);
          }
        }
      }
      __builtin_amdgcn_s_setprio(0);
    }
    __syncthreads();
    cur ^= 1;
  }

  const int b = bh >> 4, h = bh & 15;
  #pragma unroll
  for (int f = 0; f < 2; f++) {
    const int rbf = (f == 0) ? rb0 : rb1;
    #pragma unroll
    for (int dt = 0; dt < 4; dt++) {
      #pragma unroll
      for (int j = 0; j < 4; j++) {
        int row = rbf + g * 4 + j;
        float val = oacc[f][dt][j] / l_run[f][j];
        O[((size_t)(b * SS + row) << 10) + h * DK + dt * 16 + c] = f2bf(val);
      }
    }
  }
}

// ---------------- launch ----------------
extern "C" void kernel_launch(void* const* d_in, const int* in_sizes, int n_in,
                              void* d_out, int out_size, void* d_ws, size_t ws_size,
                              hipStream_t stream) {
  const float* x  = (const float*)d_in[0];
  const float* wq = (const float*)d_in[2];
  const float* bq = (const float*)d_in[3];
  const float* wk = (const float*)d_in[4];
  const float* bk = (const float*)d_in[5];
  const float* wv = (const float*)d_in[6];
  const float* bv = (const float*)d_in[7];
  const float* wo = (const float*)d_in[8];
  const float* bo = (const float*)d_in[9];

  ushort* ws = (ushort*)d_ws;
  ushort* xb = ws;                        // 4096*1024 bf16 (x) ; later reused as attn out
  ushort* wb = xb + (size_t)MM * DD;      // 1024*1024 bf16 (current weight)
  ushort* qw = wb + (size_t)DD * DD;      // 4096*1024 bf16 [B,H,S,DK]
  ushort* kw = qw + (size_t)MM * DD;      // 4096*1024 bf16 [B,H,S,DK]
  ushort* vw = kw + (size_t)MM * DD;      // 4096*1024 bf16 [B,H,DK,S]
  ushort* aw = xb;                        // attn output aliases xb (xb dead after V gemm)

  dim3 gg(DD / 128, MM / 128);

  cvt_f32_bf16<<<2048, 256, 0, stream>>>(x, xb, MM * DD / 4);

  cvt_f32_bf16<<<512, 256, 0, stream>>>(wq, wb, DD * DD / 4);
  gemm_nt<0><<<gg, 256, 0, stream>>>(xb, wb, bq, qw, 0.125f);   // Q, pre-scaled 1/sqrt(64)

  cvt_f32_bf16<<<512, 256, 0, stream>>>(wk, wb, DD * DD / 4);
  gemm_nt<0><<<gg, 256, 0, stream>>>(xb, wb, bk, kw, 1.0f);     // K

  cvt_f32_bf16<<<512, 256, 0, stream>>>(wv, wb, DD * DD / 4);
  gemm_nt<1><<<gg, 256, 0, stream>>>(xb, wb, bv, vw, 1.0f);     // V (transposed [B,H,DK,S])

  attn_fwd<<<dim3(16, BB * HH), 256, 0, stream>>>(qw, kw, vw, aw);

  cvt_f32_bf16<<<512, 256, 0, stream>>>(wo, wb, DD * DD / 4);
  gemm_nt<2><<<gg, 256, 0, stream>>>(aw, wb, bo, d_out, 1.0f);  // final, fp32 out
}

// Round 4
// 157.532 us; speedup vs baseline: 2.1988x; 1.1006x over previous
//
#include <hip/hip_runtime.h>
#include <hip/hip_bf16.h>

#define BB 2
#define SS 2048
#define DD 1024
#define HH 16
#define DK 64
#define MM (BB*SS)   // 4096

typedef __attribute__((ext_vector_type(8))) short bf16x8;
typedef __attribute__((ext_vector_type(4))) float f32x4;

__device__ inline ushort f2bf(float f) {
  __hip_bfloat16 h = __float2bfloat16(f);
  return *reinterpret_cast<ushort*>(&h);
}

// hardware exp2 (single v_exp_f32)
__device__ __forceinline__ float exp2_hw(float x) {
  float r; asm("v_exp_f32 %0, %1" : "=v"(r) : "v"(x)); return r;
}

// async global->LDS, 16B per lane. ldst must be wave-uniform; HW adds lane*16.
__device__ __forceinline__ void gl_lds16(const ushort* g, ushort* l) {
  __builtin_amdgcn_global_load_lds((const __attribute__((address_space(1))) void*)g,
                                   (__attribute__((address_space(3))) void*)l, 16, 0, 0);
}

// ---------------- fp32 -> bf16 convert (float4 vectorized) ----------------
__global__ void cvt_f32_bf16(const float* __restrict__ src, ushort* __restrict__ dst, int n4) {
  int i = blockIdx.x * blockDim.x + threadIdx.x;
  int stride = gridDim.x * blockDim.x;
  for (int idx = i; idx < n4; idx += stride) {
    float4 v = reinterpret_cast<const float4*>(src)[idx];
    ushort4 o;
    o.x = f2bf(v.x); o.y = f2bf(v.y); o.z = f2bf(v.z); o.w = f2bf(v.w);
    reinterpret_cast<ushort4*>(dst)[idx] = o;
  }
}

// ---------------- GEMM NT: C[m,e] = sum_k A[m,k] * W[e,k]  (+bias)*scale ----
// 64x128 tile, BK=64, double-buffered LDS via global_load_lds, XOR swizzle.
// LAYOUT 0: bf16 out, [B,H,S,DK] (Q,K)   LAYOUT 1: bf16 out, [B,H,DK,S] (V)
// LAYOUT 2: fp32 out, [M,N] flat (final projection)
template<int LAYOUT>
__global__ __launch_bounds__(256, 2) void gemm_nt(const ushort* __restrict__ A,
                                                  const ushort* __restrict__ W,
                                                  const float* __restrict__ bias,
                                                  void* __restrict__ out,
                                                  float scale) {
  constexpr int K = 1024;
  __shared__ __align__(16) ushort lA[2][64 * 64];
  __shared__ __align__(16) ushort lB[2][128 * 64];
  const int t = threadIdx.x;
  const int w = t >> 6, lane = t & 63;
  const int m0 = blockIdx.y * 64, n0 = blockIdx.x * 128;
  const int wm = (w >> 1) * 32, wn = (w & 1) * 64;
  const int c = lane & 15, g = lane >> 4;

  f32x4 acc[2][4];
  #pragma unroll
  for (int i = 0; i < 2; i++)
    #pragma unroll
    for (int j = 0; j < 4; j++) acc[i][j] = f32x4{0.f, 0.f, 0.f, 0.f};

  // chunk (row,col) in LDS holds global chunk (row, col^(row&7)); 8 chunks/row.
  auto stage = [&](int ks, int buf) {
    const int k0 = ks * 64;
    #pragma unroll
    for (int i = 0; i < 2; i++) {
      int ch = i * 256 + t;
      int row = ch >> 3;
      int cs = (ch & 7) ^ (row & 7);
      gl_lds16(&A[(size_t)(m0 + row) * K + k0 + cs * 8], &lA[buf][(i * 256 + w * 64) * 8]);
    }
    #pragma unroll
    for (int i = 0; i < 4; i++) {
      int ch = i * 256 + t;
      int row = ch >> 3;
      int cs = (ch & 7) ^ (row & 7);
      gl_lds16(&W[(size_t)(n0 + row) * K + k0 + cs * 8], &lB[buf][(i * 256 + w * 64) * 8]);
    }
  };

  stage(0, 0);
  __syncthreads();
  int cur = 0;
  for (int ks = 0; ks < 16; ks++) {
    if (ks + 1 < 16) stage(ks + 1, cur ^ 1);
    #pragma unroll
    for (int kk2 = 0; kk2 < 2; kk2++) {
      bf16x8 af[2], bfr[4];
      #pragma unroll
      for (int mi = 0; mi < 2; mi++) {
        int row = wm + mi * 16 + c;
        af[mi] = *reinterpret_cast<const bf16x8*>(&lA[cur][row * 64 + (((kk2 * 4 + g) ^ (c & 7)) * 8)]);
      }
      #pragma unroll
      for (int ni = 0; ni < 4; ni++) {
        int row = wn + ni * 16 + c;
        bfr[ni] = *reinterpret_cast<const bf16x8*>(&lB[cur][row * 64 + (((kk2 * 4 + g) ^ (c & 7)) * 8)]);
      }
      #pragma unroll
      for (int mi = 0; mi < 2; mi++)
        #pragma unroll
        for (int ni = 0; ni < 4; ni++)
          acc[mi][ni] = __builtin_amdgcn_mfma_f32_16x16x32_bf16(af[mi], bfr[ni], acc[mi][ni], 0, 0, 0);
    }
    __syncthreads();
    cur ^= 1;
  }

  #pragma unroll
  for (int mi = 0; mi < 2; mi++) {
    #pragma unroll
    for (int ni = 0; ni < 4; ni++) {
      int colb = n0 + wn + ni * 16 + c;
      float bv = bias[colb];
      #pragma unroll
      for (int j = 0; j < 4; j++) {
        int row = m0 + wm + mi * 16 + g * 4 + j;
        float val = (acc[mi][ni][j] + bv) * scale;
        if (LAYOUT == 0) {        // bf16 [B,H,S,DK]
          int b = row >> 11, s = row & 2047, h = colb >> 6, dk = colb & 63;
          reinterpret_cast<ushort*>(out)[(((b * HH + h) * SS + s) << 6) + dk] = f2bf(val);
        } else if (LAYOUT == 1) { // bf16 [B,H,DK,S]
          int b = row >> 11, s = row & 2047, h = colb >> 6, dk = colb & 63;
          reinterpret_cast<ushort*>(out)[(((b * HH + h) * DK + dk) << 11) + s] = f2bf(val);
        } else {                  // fp32 [M,N]
          reinterpret_cast<float*>(out)[(row << 10) + colb] = val;
        }
      }
    }
  }
}

// ---------------- causal flash attention v4 ----------------
// Q,K: [B,H,S,DK] bf16 (Q pre-scaled by log2e/sqrt(DK)); V: [B,H,DK,S] bf16
// O: [B,S,D] bf16. Softmax in exp2 domain; row-sum l via MFMA vs all-ones.
// 4 waves/block share K/V tiles in LDS (global_load_lds, dbuf, XOR swizzle).
// Wave w owns strips a = bx*4+w and 127-a (mirror pairing -> uniform tiles).
__global__ __launch_bounds__(256, 2) void attn_fwd(const ushort* __restrict__ Q,
                                                   const ushort* __restrict__ Kk,
                                                   const ushort* __restrict__ Vt,
                                                   ushort* __restrict__ O) {
  __shared__ __align__(16) ushort ldsK[2][64 * 64];
  __shared__ __align__(16) ushort ldsV[2][64 * 64];
  __shared__ __align__(16) ushort lds_p[4][16 * 72];
  const int t0 = threadIdx.x;
  const int w = t0 >> 6;
  const int lane = t0 & 63;
  const int c = lane & 15, g = lane >> 4;
  const int bh = blockIdx.y;                 // 0..B*H-1
  const int bx = blockIdx.x;                 // 0..15
  const int a = bx * 4 + w;                  // 0..63
  const int rb0 = a * 16;                    // strip A rows
  const int rb1 = 2032 - a * 16;             // strip B rows (mirror)
  const int itB = (rb1 + 79) >> 6;           // tiles needed by strip B
  const int itMax = (2111 - 64 * bx) >> 6;   // block-uniform loop count

  const ushort* qbase = Q + (size_t)bh * SS * DK;
  const ushort* kbase = Kk + (size_t)bh * SS * DK;
  const ushort* vbase = Vt + (size_t)bh * DK * SS;

  bf16x8 onesf;
  #pragma unroll
  for (int i = 0; i < 8; i++) onesf[i] = (short)0x3F80;  // bf16 1.0

  bf16x8 qf[2][2];
  qf[0][0] = *reinterpret_cast<const bf16x8*>(&qbase[(rb0 + c) * DK + g * 8]);
  qf[0][1] = *reinterpret_cast<const bf16x8*>(&qbase[(rb0 + c) * DK + 32 + g * 8]);
  qf[1][0] = *reinterpret_cast<const bf16x8*>(&qbase[(rb1 + c) * DK + g * 8]);
  qf[1][1] = *reinterpret_cast<const bf16x8*>(&qbase[(rb1 + c) * DK + 32 + g * 8]);

  f32x4 oacc[2][4], lacc[2];
  float m_run[2][4];
  #pragma unroll
  for (int f = 0; f < 2; f++) {
    #pragma unroll
    for (int i = 0; i < 4; i++) oacc[f][i] = f32x4{0.f, 0.f, 0.f, 0.f};
    lacc[f] = f32x4{0.f, 0.f, 0.f, 0.f};
    #pragma unroll
    for (int j = 0; j < 4; j++) m_run[f][j] = -1e30f;
  }

  // K tile: 64 kv-rows x 64 dk ; V tile: 64 dk-rows x 64 kv (both XOR-swizzled)
  auto stage = [&](int tt, int buf) {
    const int kv = tt * 64;
    #pragma unroll
    for (int i = 0; i < 2; i++) {
      int ch = w * 128 + i * 64 + lane;
      int row = ch >> 3;
      int cs = (ch & 7) ^ (row & 7);
      gl_lds16(&kbase[(kv + row) * DK + cs * 8], &ldsK[buf][(w * 128 + i * 64) * 8]);
      gl_lds16(&vbase[row * SS + kv + cs * 8], &ldsV[buf][(w * 128 + i * 64) * 8]);
    }
  };

  stage(0, 0);
  __syncthreads();
  int cur = 0;

  for (int t = 0; t < itMax; ++t) {
    const int kv = t * 64;
    if (t + 1 < itMax) stage(t + 1, cur ^ 1);
    const bool actB = t < itB;
    const bool actA = kv < rb0 + 16;
    if (actA || actB) {
      // ---- K fragments from LDS (shared by both strips) ----
      bf16x8 kf[8];
      #pragma unroll
      for (int i = 0; i < 8; i++) {
        int tt = i >> 1, kk2 = i & 1;
        kf[i] = *reinterpret_cast<const bf16x8*>(
            &ldsK[cur][(tt * 16 + c) * 64 + (((kk2 * 4 + g) ^ (c & 7)) * 8)]);
      }
      // ---- QK^T (scores already in log2 domain via Q pre-scale) ----
      f32x4 s[2][4];
      __builtin_amdgcn_s_setprio(1);
      if (actB) {
        #pragma unroll
        for (int tt = 0; tt < 4; tt++) {
          f32x4 z = {0.f, 0.f, 0.f, 0.f};
          z = __builtin_amdgcn_mfma_f32_16x16x32_bf16(qf[1][0], kf[tt * 2], z, 0, 0, 0);
          s[1][tt] = __builtin_amdgcn_mfma_f32_16x16x32_bf16(qf[1][1], kf[tt * 2 + 1], z, 0, 0, 0);
        }
      }
      if (actA) {
        #pragma unroll
        for (int tt = 0; tt < 4; tt++) {
          f32x4 z = {0.f, 0.f, 0.f, 0.f};
          z = __builtin_amdgcn_mfma_f32_16x16x32_bf16(qf[0][0], kf[tt * 2], z, 0, 0, 0);
          s[0][tt] = __builtin_amdgcn_mfma_f32_16x16x32_bf16(qf[0][1], kf[tt * 2 + 1], z, 0, 0, 0);
        }
      }
      __builtin_amdgcn_s_setprio(0);

      // ---- V fragments (issue loads before softmax chains) ----
      bf16x8 vf[8];
      #pragma unroll
      for (int i = 0; i < 8; i++) {
        int dt = i >> 1, kk2 = i & 1;
        vf[i] = *reinterpret_cast<const bf16x8*>(
            &ldsV[cur][(dt * 16 + c) * 64 + (((kk2 * 4 + g) ^ (c & 7)) * 8)]);
      }

      // ---- per strip: mask + online softmax (exp2) + P->LDS + PV + l-MFMA ----
      #pragma unroll
      for (int f = 0; f < 2; f++) {
        const bool act = (f == 0) ? actA : actB;
        if (act) {
          const int rbf = (f == 0) ? rb0 : rb1;
          if (kv + 63 > rbf) {
            #pragma unroll
            for (int tt = 0; tt < 4; tt++) {
              int kj = kv + tt * 16 + c;
              #pragma unroll
              for (int j = 0; j < 4; j++) {
                int r = rbf + g * 4 + j;
                if (kj > r) s[f][tt][j] = -1e30f;
              }
            }
          }
          float mn[4], alpha[4];
          #pragma unroll
          for (int j = 0; j < 4; j++) {
            float m1 = fmaxf(fmaxf(s[f][0][j], s[f][1][j]), fmaxf(s[f][2][j], s[f][3][j]));
            #pragma unroll
            for (int off = 1; off < 16; off <<= 1)
              m1 = fmaxf(m1, __shfl_xor(m1, off, 16));
            mn[j] = fmaxf(m_run[f][j], m1);
            alpha[j] = exp2_hw(m_run[f][j] - mn[j]);
            m_run[f][j] = mn[j];
          }
          #pragma unroll
          for (int j = 0; j < 4; j++) {
            #pragma unroll
            for (int dt = 0; dt < 4; dt++) oacc[f][dt][j] *= alpha[j];
            lacc[f][j] *= alpha[j];
          }
          ushort* pb = &lds_p[w][0];
          #pragma unroll
          for (int tt = 0; tt < 4; tt++) {
            #pragma unroll
            for (int j = 0; j < 4; j++) {
              float p = exp2_hw(s[f][tt][j] - mn[j]);
              pb[(g * 4 + j) * 72 + tt * 16 + c] = f2bf(p);
            }
          }
          __builtin_amdgcn_s_setprio(1);
          #pragma unroll
          for (int kk2 = 0; kk2 < 2; kk2++) {
            bf16x8 pa = *reinterpret_cast<const bf16x8*>(&pb[c * 72 + kk2 * 32 + g * 8]);
            #pragma unroll
            for (int dt = 0; dt < 4; dt++)
              oacc[f][dt] = __builtin_amdgcn_mfma_f32_16x16x32_bf16(pa, vf[dt * 2 + kk2], oacc[f][dt], 0, 0, 0);
            lacc[f] = __builtin_amdgcn_mfma_f32_16x16x32_bf16(pa, onesf, lacc[f], 0, 0, 0);
          }
          __builtin_amdgcn_s_setprio(0);
        }
      }
    }
    __syncthreads();
    cur ^= 1;
  }

  const int b = bh >> 4, h = bh & 15;
  #pragma unroll
  for (int f = 0; f < 2; f++) {
    const int rbf = (f == 0) ? rb0 : rb1;
    #pragma unroll
    for (int dt = 0; dt < 4; dt++) {
      #pragma unroll
      for (int j = 0; j < 4; j++) {
        int row = rbf + g * 4 + j;
        float val = oacc[f][dt][j] / lacc[f][j];
        O[((size_t)(b * SS + row) << 10) + h * DK + dt * 16 + c] = f2bf(val);
      }
    }
  }
}

// ---------------- launch ----------------
extern "C" void kernel_launch(void* const* d_in, const int* in_sizes, int n_in,
                              void* d_out, int out_size, void* d_ws, size_t ws_size,
                              hipStream_t stream) {
  const float* x  = (const float*)d_in[0];
  const float* wq = (const float*)d_in[2];
  const float* bq = (const float*)d_in[3];
  const float* wk = (const float*)d_in[4];
  const float* bk = (const float*)d_in[5];
  const float* wv = (const float*)d_in[6];
  const float* bv = (const float*)d_in[7];
  const float* wo = (const float*)d_in[8];
  const float* bo = (const float*)d_in[9];

  ushort* ws = (ushort*)d_ws;
  ushort* xb = ws;                        // 4096*1024 bf16 (x) ; later reused as attn out
  ushort* wb = xb + (size_t)MM * DD;      // 1024*1024 bf16 (current weight)
  ushort* qw = wb + (size_t)DD * DD;      // 4096*1024 bf16 [B,H,S,DK]
  ushort* kw = qw + (size_t)MM * DD;      // 4096*1024 bf16 [B,H,S,DK]
  ushort* vw = kw + (size_t)MM * DD;      // 4096*1024 bf16 [B,H,DK,S]
  ushort* aw = xb;                        // attn output aliases xb (xb dead after V gemm)

  dim3 gg(DD / 128, MM / 64);
  const float qscale = 0.18033688011112043f;  // (1/8) * log2(e)

  cvt_f32_bf16<<<2048, 256, 0, stream>>>(x, xb, MM * DD / 4);

  cvt_f32_bf16<<<512, 256, 0, stream>>>(wq, wb, DD * DD / 4);
  gemm_nt<0><<<gg, 256, 0, stream>>>(xb, wb, bq, qw, qscale);   // Q (log2-domain scale)

  cvt_f32_bf16<<<512, 256, 0, stream>>>(wk, wb, DD * DD / 4);
  gemm_nt<0><<<gg, 256, 0, stream>>>(xb, wb, bk, kw, 1.0f);     // K

  cvt_f32_bf16<<<512, 256, 0, stream>>>(wv, wb, DD * DD / 4);
  gemm_nt<1><<<gg, 256, 0, stream>>>(xb, wb, bv, vw, 1.0f);     // V (transposed [B,H,DK,S])

  attn_fwd<<<dim3(16, BB * HH), 256, 0, stream>>>(qw, kw, vw, aw);

  cvt_f32_bf16<<<512, 256, 0, stream>>>(wo, wb, DD * DD / 4);
  gemm_nt<2><<<gg, 256, 0, stream>>>(aw, wb, bo, d_out, 1.0f);  // final, fp32 out
}